// Round 6
// baseline (85.122 us; speedup 1.0000x reference)
//
#include <hip/hip_runtime.h>
#include <stdint.h>
#include <math.h>

constexpr int NB = 8;
constexpr int NC = 32;
constexpr int NK = 512;
constexpr int ROWS = 4;          // rows (i) per block

// ---------------------------------------------------------------------------
// Threefry2x32 (Random123 / JAX), key = (0, 42), x0 = 0 (flat idx < 2^32)
// partitionable mode: bits(n) = o0 ^ o1
// ---------------------------------------------------------------------------
__device__ __forceinline__ uint32_t rotl32(uint32_t x, uint32_t r) {
    return (x << r) | (x >> (32u - r));
}

__device__ __forceinline__ uint32_t jax_random_bits(uint32_t n) {
    const uint32_t k0 = 0u, k1 = 42u;
    const uint32_t ks2 = k0 ^ k1 ^ 0x1BD11BDAu;
    uint32_t x0 = 0u + k0, x1 = n + k1;

    x0 += x1; x1 = rotl32(x1, 13); x1 ^= x0;
    x0 += x1; x1 = rotl32(x1, 15); x1 ^= x0;
    x0 += x1; x1 = rotl32(x1, 26); x1 ^= x0;
    x0 += x1; x1 = rotl32(x1,  6); x1 ^= x0;
    x0 += k1; x1 += ks2 + 1u;

    x0 += x1; x1 = rotl32(x1, 17); x1 ^= x0;
    x0 += x1; x1 = rotl32(x1, 29); x1 ^= x0;
    x0 += x1; x1 = rotl32(x1, 16); x1 ^= x0;
    x0 += x1; x1 = rotl32(x1, 24); x1 ^= x0;
    x0 += ks2; x1 += k0 + 2u;

    x0 += x1; x1 = rotl32(x1, 13); x1 ^= x0;
    x0 += x1; x1 = rotl32(x1, 15); x1 ^= x0;
    x0 += x1; x1 = rotl32(x1, 26); x1 ^= x0;
    x0 += x1; x1 = rotl32(x1,  6); x1 ^= x0;
    x0 += k0; x1 += k1 + 3u;

    x0 += x1; x1 = rotl32(x1, 17); x1 ^= x0;
    x0 += x1; x1 = rotl32(x1, 29); x1 ^= x0;
    x0 += x1; x1 = rotl32(x1, 16); x1 ^= x0;
    x0 += x1; x1 = rotl32(x1, 24); x1 ^= x0;
    x0 += k1; x1 += ks2 + 4u;

    x0 += x1; x1 = rotl32(x1, 13); x1 ^= x0;
    x0 += x1; x1 = rotl32(x1, 15); x1 ^= x0;
    x0 += x1; x1 = rotl32(x1, 26); x1 ^= x0;
    x0 += x1; x1 = rotl32(x1,  6); x1 ^= x0;
    x0 += ks2; x1 += k0 + 5u;

    return x0 ^ x1;
}

// u (f64, JAX-exact) and fast f32 L = -log(u).
__device__ __forceinline__ float fastL(uint32_t bits, double& ud) {
    const double S = 1.0 - 1e-10, T = 1e-10;
    uint32_t fb = (bits >> 9) | 0x3F800000u;
    float bf = __uint_as_float(fb) - 1.0f;            // exact 23-bit uniform [0,1)
    ud = (double)bf * S + T;                          // >= 1e-10 by construction
    if (bf <= 0.5f) {
        return -logf((float)ud);
    } else {
        double vm1 = S * ((double)bf - 1.0);          // u-1 in f64 (no cancel loss)
        return -log1pf((float)vm1);
    }
}

// rare exact-path fallback
__device__ __noinline__ bool decide_slow(double a2, double c2,
                                         double u0, double u1) {
    return a2 * (-log(u1)) >= c2 * (-log(u0));
}

// ---------------------------------------------------------------------------
// Prep (R2-proven): zero out (262144 f32 == grid), F = wa*amp+wp*ph (f64, ws),
// A2[j] = A_jj^2.  grid 1024 x 256.
// ---------------------------------------------------------------------------
__global__ void prep_kernel(const float* __restrict__ amp,
                            const float* __restrict__ ph,
                            const float* __restrict__ A,
                            const float* __restrict__ wav,
                            const float* __restrict__ wpv,
                            double* __restrict__ F,
                            double* __restrict__ A2,
                            float* __restrict__ out) {
    int t = blockIdx.x * 256 + threadIdx.x;
    out[t] = 0.0f;
    if (t < NB * NC * NK) {
        double wa = (double)wav[0], wp = (double)wpv[0];
        F[t] = wa * (double)amp[t] + wp * (double)ph[t];
    }
    if (t < NK) {
        double a = (double)A[t * NK + t];
        A2[t] = a * a;
    }
}

// ---------------------------------------------------------------------------
// Main: grid (NK/ROWS, NB) x 256. Thread owns cols j = 2*tid, 2*tid+1 for
// ROWS rows. Wave w owns j in [128w, 128w+128): wave-local compaction
// (R5-proven; no cross-wave state). Phase 3 uses STAGED RNG: L0 first,
// conservative skip (L1 <= 23.02585 exact bound), then L1 only if needed.
// ---------------------------------------------------------------------------
__global__ __launch_bounds__(256) void sample_kernel(
    const double* __restrict__ F, const double* __restrict__ A2,
    float* __restrict__ out)
{
    const int i0   = blockIdx.x * ROWS;
    const int b    = blockIdx.y;
    const int tid  = threadIdx.x;
    const int j0   = 2 * tid;
    const int lane = tid & 63;
    const int wv   = tid >> 6;          // wave index 0..3
    const int wjb  = wv * 128;          // wave's j base

    __shared__ unsigned char wlist[4][ROWS][128];   // wave-private lists, 2 KB
    __shared__ double sred[ROWS][4];
    __shared__ double s_q[ROWS];

    const double* __restrict__ Fb = F + (size_t)b * NC * NK;

    // ---- Phase 1: dist accumulation (same per-element fma chain as R1-R5)
    double acc[2][ROWS];
    #pragma unroll
    for (int it = 0; it < 2; ++it)
        #pragma unroll
        for (int r = 0; r < ROWS; ++r) acc[it][r] = 0.0;

    #pragma unroll 8
    for (int c = 0; c < NC; ++c) {
        double fi_r[ROWS];
        #pragma unroll
        for (int r = 0; r < ROWS; ++r)
            fi_r[r] = Fb[c * NK + i0 + r];          // uniform -> scalar loads
        double2 fj = *(const double2*)(Fb + c * NK + j0);   // 16B coalesced
        #pragma unroll
        for (int r = 0; r < ROWS; ++r) {
            double d0 = fi_r[r] - fj.x; acc[0][r] = fma(d0, d0, acc[0][r]);
            double d1 = fi_r[r] - fj.y; acc[1][r] = fma(d1, d1, acc[1][r]);
        }
    }

    double2 a2j = *(const double2*)(A2 + j0);
    double D[2][ROWS];
    #pragma unroll
    for (int r = 0; r < ROWS; ++r) {
        D[0][r] = acc[0][r] * a2j.x + 1e-10;   // same rounding as R1-R5
        D[1][r] = acc[1][r] * a2j.y + 1e-10;
    }

    // per-row min over j != i (exact, order-independent; proven path)
    #pragma unroll
    for (int r = 0; r < ROWS; ++r) {
        const int i = i0 + r;
        double m = 1e300;
        if (j0     != i) m = fmin(m, D[0][r]);
        if (j0 + 1 != i) m = fmin(m, D[1][r]);
        #pragma unroll
        for (int off = 32; off > 0; off >>= 1)
            m = fmin(m, __shfl_down(m, off));
        if (lane == 0) sred[r][wv] = m;
    }
    __syncthreads();
    if (tid < ROWS) {
        double m = fmin(fmin(sred[tid][0], sred[tid][1]),
                        fmin(sred[tid][2], sred[tid][3]));
        s_q[tid] = 0.99 * m;
    }
    __syncthreads();

    // ---- Phase 2: stage-1 deterministic-false filter + WAVE-LOCAL compaction
    // Skip iff (D-q)^2 > 1.95e8*q^2 (false for ANY draw; 1% log-margin, f64).
    const unsigned long long ltmask = (1ull << lane) - 1ull;
    int nw[ROWS];
    #pragma unroll
    for (int r = 0; r < ROWS; ++r) {
        const int i = i0 + r;
        const double q = s_q[r];
        const double thr = 1.95e8 * (q * q);
        double t0 = D[0][r] - q;
        double t1 = D[1][r] - q;
        bool need0 = (j0     == i) || !(t0 * t0 > thr);
        bool need1 = (j0 + 1 == i) || !(t1 * t1 > thr);
        unsigned long long m0 = __ballot(need0);
        unsigned long long m1 = __ballot(need1);
        int c0 = __popcll(m0);
        nw[r] = c0 + __popcll(m1);
        if (need0) wlist[wv][r][__popcll(m0 & ltmask)]      = (unsigned char)(2 * lane);
        if (need1) wlist[wv][r][c0 + __popcll(m1 & ltmask)] = (unsigned char)(2 * lane + 1);
    }
    // same-wave LDS RAW: ordered by program order + lgkmcnt, no barrier needed

    // ---- Phase 3: staged RNG over the wave's own list.
    // decision: a2*L1 >= c2*L0.  Stage 2: draw L0 only; skip-as-false iff
    // c2*L0_lo > 23.03*a2  (L1 <= -ln(1e-10) = 23.025850929... in f64; skip
    // margin >= 1.5e-4 rel, safely outside the 1e-4 fast-path fence).
    // Stage 3 (rare): draw L1, f32 fenced compare, f64 fallback.
    #pragma unroll
    for (int r = 0; r < ROWS; ++r) {
        const int i = i0 + r;
        const double q = s_q[r];
        const int n = nw[r];                 // wave-uniform (from ballots)
        for (int k0v = 0; k0v < n; k0v += 64) {
            int k = k0v + lane;
            bool act = k < n;
            int jl = wlist[wv][r][act ? k : 0];   // in-bounds always
            int src = jl >> 1;
            // all-lane shfls (loop bound wave-uniform; before any divergence)
            double d0s = __shfl(D[0][r], src);
            double d1s = __shfl(D[1][r], src);
            double Dv = (jl & 1) ? d1s : d0s;
            int j = wjb + jl;

            double a2, c2;
            if (j == i) { a2 = 9801.0; c2 = 1.0; }
            else        { a2 = q * q; double t = Dv - q; c2 = t * t; }

            uint32_t n0 = 2u * (((uint32_t)(b * NK + i)) * NK + (uint32_t)j);
            bool hit = false;
            if (act) {
                uint32_t bits0 = jax_random_bits(n0);
                double u0d;
                float L0f = fastL(bits0, u0d);
                float L0lo = L0f * 0.99999f;
                // stage-2 conservative skip (provably false for any u1)
                if (!((double)c2 * (double)L0lo > 23.03 * a2)) {
                    uint32_t bits1 = jax_random_bits(n0 + 1u);
                    double u1d;
                    float L1f = fastL(bits1, u1d);
                    float lhs = (float)a2 * L1f;
                    float rhs = (float)c2 * L0f;
                    float diff = lhs - rhs;
                    if (fabsf(diff) > 1e-4f * (lhs + rhs))
                        hit = diff >= 0.0f;           // fast path, sign-safe
                    else
                        hit = decide_slow(a2, c2, u0d, u1d);
                }
            }
            if (hit)
                atomicAdd(&out[i * NK + j], 0.125f);  // mean over B=8, exact
        }
    }
}

extern "C" void kernel_launch(void* const* d_in, const int* in_sizes, int n_in,
                              void* d_out, int out_size, void* d_ws, size_t ws_size,
                              hipStream_t stream) {
    const float* amp = (const float*)d_in[0];   // (8,32,512)
    const float* ph  = (const float*)d_in[1];   // (8,32,512)
    const float* A   = (const float*)d_in[2];   // (512,512)
    const float* wa  = (const float*)d_in[3];   // scalar
    const float* wp  = (const float*)d_in[4];   // scalar
    float* out = (float*)d_out;                 // (512,512) f32

    double* F  = (double*)d_ws;                    // 131072 f64 = 1 MB
    double* A2 = (double*)d_ws + NB * NC * NK;     // 512 f64

    prep_kernel<<<1024, 256, 0, stream>>>(amp, ph, A, wa, wp, F, A2, out);

    dim3 grid(NK / ROWS, NB);
    sample_kernel<<<grid, 256, 0, stream>>>(F, A2, out);
}

// Round 7
// 79.222 us; speedup vs baseline: 1.0745x; 1.0745x over previous
//
#include <hip/hip_runtime.h>
#include <stdint.h>
#include <math.h>

constexpr int NB = 8;
constexpr int NC = 32;
constexpr int NK = 512;
constexpr int ROWS = 4;          // rows (i) per block

// ---------------------------------------------------------------------------
// Threefry2x32 (Random123 / JAX), key = (0, 42), x0 = 0 (flat idx < 2^32)
// partitionable mode: bits(n) = o0 ^ o1
// ---------------------------------------------------------------------------
__device__ __forceinline__ uint32_t rotl32(uint32_t x, uint32_t r) {
    return (x << r) | (x >> (32u - r));
}

__device__ __forceinline__ uint32_t jax_random_bits(uint32_t n) {
    const uint32_t k0 = 0u, k1 = 42u;
    const uint32_t ks2 = k0 ^ k1 ^ 0x1BD11BDAu;
    uint32_t x0 = 0u + k0, x1 = n + k1;

    x0 += x1; x1 = rotl32(x1, 13); x1 ^= x0;
    x0 += x1; x1 = rotl32(x1, 15); x1 ^= x0;
    x0 += x1; x1 = rotl32(x1, 26); x1 ^= x0;
    x0 += x1; x1 = rotl32(x1,  6); x1 ^= x0;
    x0 += k1; x1 += ks2 + 1u;

    x0 += x1; x1 = rotl32(x1, 17); x1 ^= x0;
    x0 += x1; x1 = rotl32(x1, 29); x1 ^= x0;
    x0 += x1; x1 = rotl32(x1, 16); x1 ^= x0;
    x0 += x1; x1 = rotl32(x1, 24); x1 ^= x0;
    x0 += ks2; x1 += k0 + 2u;

    x0 += x1; x1 = rotl32(x1, 13); x1 ^= x0;
    x0 += x1; x1 = rotl32(x1, 15); x1 ^= x0;
    x0 += x1; x1 = rotl32(x1, 26); x1 ^= x0;
    x0 += x1; x1 = rotl32(x1,  6); x1 ^= x0;
    x0 += k0; x1 += k1 + 3u;

    x0 += x1; x1 = rotl32(x1, 17); x1 ^= x0;
    x0 += x1; x1 = rotl32(x1, 29); x1 ^= x0;
    x0 += x1; x1 = rotl32(x1, 16); x1 ^= x0;
    x0 += x1; x1 = rotl32(x1, 24); x1 ^= x0;
    x0 += k1; x1 += ks2 + 4u;

    x0 += x1; x1 = rotl32(x1, 13); x1 ^= x0;
    x0 += x1; x1 = rotl32(x1, 15); x1 ^= x0;
    x0 += x1; x1 = rotl32(x1, 26); x1 ^= x0;
    x0 += x1; x1 = rotl32(x1,  6); x1 ^= x0;
    x0 += ks2; x1 += k0 + 5u;

    return x0 ^ x1;
}

// u (f64, JAX-exact) and fast f32 L = -log(u).
__device__ __forceinline__ float fastL(uint32_t bits, double& ud) {
    const double S = 1.0 - 1e-10, T = 1e-10;
    uint32_t fb = (bits >> 9) | 0x3F800000u;
    float bf = __uint_as_float(fb) - 1.0f;            // exact 23-bit uniform [0,1)
    ud = (double)bf * S + T;                          // >= 1e-10 by construction
    if (bf <= 0.5f) {
        return -logf((float)ud);
    } else {
        double vm1 = S * ((double)bf - 1.0);          // u-1 in f64 (no cancel loss)
        return -log1pf((float)vm1);
    }
}

// rare exact-path fallback
__device__ __noinline__ bool decide_slow(double a2, double c2,
                                         double u0, double u1) {
    return a2 * (-log(u1)) >= c2 * (-log(u0));
}

// ---------------------------------------------------------------------------
// Prep (R2-proven): zero out (262144 f32 == grid), F = wa*amp+wp*ph (f64, ws),
// A2[j] = A_jj^2.  grid 1024 x 256.
// ---------------------------------------------------------------------------
__global__ void prep_kernel(const float* __restrict__ amp,
                            const float* __restrict__ ph,
                            const float* __restrict__ A,
                            const float* __restrict__ wav,
                            const float* __restrict__ wpv,
                            double* __restrict__ F,
                            double* __restrict__ A2,
                            float* __restrict__ out) {
    int t = blockIdx.x * 256 + threadIdx.x;
    out[t] = 0.0f;
    if (t < NB * NC * NK) {
        double wa = (double)wav[0], wp = (double)wpv[0];
        F[t] = wa * (double)amp[t] + wp * (double)ph[t];
    }
    if (t < NK) {
        double a = (double)A[t * NK + t];
        A2[t] = a * a;
    }
}

// ---------------------------------------------------------------------------
// Main: grid (NK/ROWS, NB) x 256. Thread owns cols j = 2*tid, 2*tid+1 for
// ROWS rows. Wave w owns j in [128w, 128w+128). All compaction state is
// WAVE-LOCAL (R5-proven). NEW in R7: the ROWS survivor lists are FUSED into
// one per-wave worklist (entry = (r<<8)|jl) so phase 3 runs full-occupancy
// iterations; D is mirrored into wave-private LDS for dynamic (r,jl) access.
// ---------------------------------------------------------------------------
__global__ __launch_bounds__(256) void sample_kernel(
    const double* __restrict__ F, const double* __restrict__ A2,
    float* __restrict__ out)
{
    const int i0   = blockIdx.x * ROWS;
    const int b    = blockIdx.y;
    const int tid  = threadIdx.x;
    const int j0   = 2 * tid;
    const int lane = tid & 63;
    const int wv   = tid >> 6;          // wave index 0..3
    const int wjb  = wv * 128;          // wave's j base

    __shared__ double Dsh[4][ROWS][128];            // wave-private D mirror, 16 KB
    __shared__ unsigned short wlist[4][ROWS * 128]; // fused wave lists, 4 KB
    __shared__ double sred[ROWS][4];
    __shared__ double s_q[ROWS];

    const double* __restrict__ Fb = F + (size_t)b * NC * NK;

    // ---- Phase 1: dist accumulation (same per-element fma chain as R1-R6)
    double acc[2][ROWS];
    #pragma unroll
    for (int it = 0; it < 2; ++it)
        #pragma unroll
        for (int r = 0; r < ROWS; ++r) acc[it][r] = 0.0;

    #pragma unroll 8
    for (int c = 0; c < NC; ++c) {
        double fi_r[ROWS];
        #pragma unroll
        for (int r = 0; r < ROWS; ++r)
            fi_r[r] = Fb[c * NK + i0 + r];          // uniform -> scalar loads
        double2 fj = *(const double2*)(Fb + c * NK + j0);   // 16B coalesced
        #pragma unroll
        for (int r = 0; r < ROWS; ++r) {
            double d0 = fi_r[r] - fj.x; acc[0][r] = fma(d0, d0, acc[0][r]);
            double d1 = fi_r[r] - fj.y; acc[1][r] = fma(d1, d1, acc[1][r]);
        }
    }

    double2 a2j = *(const double2*)(A2 + j0);
    double D[2][ROWS];
    #pragma unroll
    for (int r = 0; r < ROWS; ++r) {
        D[0][r] = acc[0][r] * a2j.x + 1e-10;   // same rounding as R1-R6
        D[1][r] = acc[1][r] * a2j.y + 1e-10;
        // wave-private mirror for dynamic-(r,jl) access in phase 3
        *(double2*)&Dsh[wv][r][2 * lane] = make_double2(D[0][r], D[1][r]);
    }

    // per-row min over j != i (exact, order-independent; proven path)
    #pragma unroll
    for (int r = 0; r < ROWS; ++r) {
        const int i = i0 + r;
        double m = 1e300;
        if (j0     != i) m = fmin(m, D[0][r]);
        if (j0 + 1 != i) m = fmin(m, D[1][r]);
        #pragma unroll
        for (int off = 32; off > 0; off >>= 1)
            m = fmin(m, __shfl_down(m, off));
        if (lane == 0) sred[r][wv] = m;
    }
    __syncthreads();
    if (tid < ROWS) {
        double m = fmin(fmin(sred[tid][0], sred[tid][1]),
                        fmin(sred[tid][2], sred[tid][3]));
        s_q[tid] = 0.99 * m;
    }
    __syncthreads();

    // ---- Phase 2: stage-1 deterministic-false filter + FUSED wave-local list
    // Skip iff (D-q)^2 > 1.95e8*q^2 (false for ANY draw; 1% log-margin, f64).
    const unsigned long long ltmask = (1ull << lane) - 1ull;
    int nb = 0;                                  // wave-uniform running count
    #pragma unroll
    for (int r = 0; r < ROWS; ++r) {
        const int i = i0 + r;
        const double q = s_q[r];
        const double thr = 1.95e8 * (q * q);
        double t0 = D[0][r] - q;
        double t1 = D[1][r] - q;
        bool need0 = (j0     == i) || !(t0 * t0 > thr);
        bool need1 = (j0 + 1 == i) || !(t1 * t1 > thr);
        unsigned long long m0 = __ballot(need0);
        unsigned long long m1 = __ballot(need1);
        int c0 = __popcll(m0);
        if (need0) wlist[wv][nb + __popcll(m0 & ltmask)] =
            (unsigned short)((r << 8) | (2 * lane));
        if (need1) wlist[wv][nb + c0 + __popcll(m1 & ltmask)] =
            (unsigned short)((r << 8) | (2 * lane + 1));
        nb += c0 + __popcll(m1);
    }
    // same-wave LDS RAW: ordered by program order + lgkmcnt, no barrier needed

    // ---- Phase 3: staged RNG over the fused wave list (full-occupancy iters)
    for (int k0v = 0; k0v < nb; k0v += 64) {
        int k = k0v + lane;
        bool act = k < nb;
        int e  = wlist[wv][act ? k : 0];          // in-bounds always
        int r  = e >> 8;
        int jl = e & 255;
        double Dv = Dsh[wv][r][jl];
        double q  = s_q[r];
        const int i = i0 + r;
        const int j = wjb + jl;

        double a2, c2;
        if (j == i) { a2 = 9801.0; c2 = 1.0; }
        else        { a2 = q * q; double t = Dv - q; c2 = t * t; }

        uint32_t n0 = 2u * (((uint32_t)(b * NK + i)) * NK + (uint32_t)j);
        bool hit = false;
        if (act) {
            uint32_t bits0 = jax_random_bits(n0);
            double u0d;
            float L0f = fastL(bits0, u0d);
            float L0lo = L0f * 0.99999f;
            // stage-2 conservative skip: provably false for any u1
            // (L1 <= -ln(1e-10) = 23.0258509...; margin >= 1.5e-4 rel)
            if (!((double)c2 * (double)L0lo > 23.03 * a2)) {
                uint32_t bits1 = jax_random_bits(n0 + 1u);
                double u1d;
                float L1f = fastL(bits1, u1d);
                float lhs = (float)a2 * L1f;
                float rhs = (float)c2 * L0f;
                float diff = lhs - rhs;
                if (fabsf(diff) > 1e-4f * (lhs + rhs))
                    hit = diff >= 0.0f;               // fast path, sign-safe
                else
                    hit = decide_slow(a2, c2, u0d, u1d);
            }
        }
        if (hit)
            atomicAdd(&out[i * NK + j], 0.125f);      // mean over B=8, exact
    }
}

extern "C" void kernel_launch(void* const* d_in, const int* in_sizes, int n_in,
                              void* d_out, int out_size, void* d_ws, size_t ws_size,
                              hipStream_t stream) {
    const float* amp = (const float*)d_in[0];   // (8,32,512)
    const float* ph  = (const float*)d_in[1];   // (8,32,512)
    const float* A   = (const float*)d_in[2];   // (512,512)
    const float* wa  = (const float*)d_in[3];   // scalar
    const float* wp  = (const float*)d_in[4];   // scalar
    float* out = (float*)d_out;                 // (512,512) f32

    double* F  = (double*)d_ws;                    // 131072 f64 = 1 MB
    double* A2 = (double*)d_ws + NB * NC * NK;     // 512 f64

    prep_kernel<<<1024, 256, 0, stream>>>(amp, ph, A, wa, wp, F, A2, out);

    dim3 grid(NK / ROWS, NB);
    sample_kernel<<<grid, 256, 0, stream>>>(F, A2, out);
}